// Round 9
// baseline (218.472 us; speedup 1.0000x reference)
//
#include <hip/hip_runtime.h>
#include <hip/hip_cooperative_groups.h>
#include <math.h>

namespace cg = cooperative_groups;

// Problem constants: B=1, S=256, HID=1024, H=16, KV=8, D=64, N_REP=2
#define SCALE 0.125f   // 1/sqrt(64)
#define LOG2E 1.44269504088896340736f

typedef short short8 __attribute__((ext_vector_type(8)));
typedef float floatx4 __attribute__((ext_vector_type(4)));

static __device__ __forceinline__ ushort f2bf(float x) {
  uint32_t b = __float_as_uint(x);
  uint32_t r = (b + 0x7FFFu + ((b >> 16) & 1u)) >> 16;   // RNE
  return (ushort)r;
}

// ---------------------------------------------------------------------------
// ONE cooperative kernel; 6 phases separated by grid.sync().
// grid = 256 WGs x 256 threads; LDS union 144KB -> 1 WG/CU (co-residency ok).
// ---------------------------------------------------------------------------
__global__ __launch_bounds__(256) void fused_kernel(
    const float* __restrict__ X, const float* __restrict__ cosp,
    const float* __restrict__ sinp, const float* __restrict__ Wq,
    const float* __restrict__ Wk, const float* __restrict__ Wv,
    const float* __restrict__ Wo, float* __restrict__ out,
    float* __restrict__ pOut, float* __restrict__ qki,
    float* __restrict__ vi, float* __restrict__ oi,
    float* __restrict__ QKV, float* __restrict__ P2g,
    float* __restrict__ attn_out, float* __restrict__ qkpart,
    float* __restrict__ awf, float* __restrict__ scratch) {
  cg::grid_group gg = cg::this_grid();
  __shared__ __align__(16) char ldsraw[147456];
  const int bid = blockIdx.x;
  const int t = threadIdx.x;
  const int wid = t >> 6, lane = t & 63;
  const int lr = lane & 15, lk = lane >> 4;
  const int sw = (lr & 7) << 4;

  // ======== Phase A: QKV GEMM bf16 MFMA, K-split 2 (verified R6) ========
  {
    char* Asc = ldsraw;
    char* Bsc = ldsraw + 8192;
    const int ks = bid >> 7;           // 0..1
    const int tile = bid & 127;        // 4 m x 32 n
    const int tile_n = tile & 31, tile_m = tile >> 5;
    const int n0 = tile_n * 64, m0 = tile_m * 64;
    const float* Bp; int ldb, bc0;
    if (n0 < 1024)      { Bp = Wq; ldb = 1024; bc0 = n0; }
    else if (n0 < 1536) { Bp = Wk; ldb = 512;  bc0 = n0 - 1024; }
    else                { Bp = Wv; ldb = 512;  bc0 = n0 - 1536; }
    const int arow = t >> 4, acg = t & 15;
    const int bng = t & 15;
    const int kbeg = ks * 512;
    float4 ra[4], rb0[2], rb1[2];
    auto LOAD = [&](int k0) {
      #pragma unroll
      for (int i = 0; i < 4; ++i)
        ra[i] = *reinterpret_cast<const float4*>(X + (size_t)(m0 + arow + 16 * i) * 1024 + k0 + acg * 4);
      #pragma unroll
      for (int i = 0; i < 2; ++i) {
        int k = 2 * ((t >> 4) + 16 * i);
        rb0[i] = *reinterpret_cast<const float4*>(Bp + (size_t)(k0 + k) * ldb + bc0 + bng * 4);
        rb1[i] = *reinterpret_cast<const float4*>(Bp + (size_t)(k0 + k + 1) * ldb + bc0 + bng * 4);
      }
    };
    LOAD(kbeg);
    const int wr = wid >> 1, wc = wid & 1;
    floatx4 acc[2][2];
    #pragma unroll
    for (int mt = 0; mt < 2; ++mt)
      #pragma unroll
      for (int nt = 0; nt < 2; ++nt)
        acc[mt][nt] = (floatx4){0.f, 0.f, 0.f, 0.f};
    for (int kt = 0; kt < 8; ++kt) {
      #pragma unroll
      for (int i = 0; i < 4; ++i) {
        int row = arow + 16 * i;
        ushort4 w;
        w.x = f2bf(ra[i].x); w.y = f2bf(ra[i].y); w.z = f2bf(ra[i].z); w.w = f2bf(ra[i].w);
        *reinterpret_cast<ushort4*>(Asc + row * 128 + ((acg * 8) ^ ((row & 7) << 4))) = w;
      }
      #pragma unroll
      for (int i = 0; i < 2; ++i) {
        int k = 2 * ((t >> 4) + 16 * i);
        const float* p0 = (const float*)&rb0[i];
        const float* p1 = (const float*)&rb1[i];
        #pragma unroll
        for (int j = 0; j < 4; ++j) {
          int n = bng * 4 + j;
          uint32_t v = (uint32_t)f2bf(p0[j]) | ((uint32_t)f2bf(p1[j]) << 16);
          *reinterpret_cast<uint32_t*>(Bsc + n * 128 + ((k * 2) ^ ((n & 7) << 4))) = v;
        }
      }
      __syncthreads();
      if (kt + 1 < 8) LOAD(kbeg + 64 * (kt + 1));
      #pragma unroll
      for (int kc = 0; kc < 2; ++kc) {
        short8 af[2], bf[2];
        #pragma unroll
        for (int mt = 0; mt < 2; ++mt)
          af[mt] = *reinterpret_cast<const short8*>(
              Asc + (wr * 32 + mt * 16 + lr) * 128 + ((kc * 64 + lk * 16) ^ sw));
        #pragma unroll
        for (int nt = 0; nt < 2; ++nt)
          bf[nt] = *reinterpret_cast<const short8*>(
              Bsc + (wc * 32 + nt * 16 + lr) * 128 + ((kc * 64 + lk * 16) ^ sw));
        #pragma unroll
        for (int mt = 0; mt < 2; ++mt)
          #pragma unroll
          for (int nt = 0; nt < 2; ++nt)
            acc[mt][nt] = __builtin_amdgcn_mfma_f32_16x16x32_bf16(af[mt], bf[nt], acc[mt][nt], 0, 0, 0);
      }
      __syncthreads();
    }
    float* Co = scratch + (size_t)ks * 524288;
    #pragma unroll
    for (int mt = 0; mt < 2; ++mt)
      #pragma unroll
      for (int nt = 0; nt < 2; ++nt)
        #pragma unroll
        for (int r = 0; r < 4; ++r) {
          int row = wr * 32 + mt * 16 + lk * 4 + r;
          int col = wc * 32 + nt * 16 + lr;
          Co[(size_t)(m0 + row) * 2048 + n0 + col] = acc[mt][nt][r];
        }
  }
  gg.sync();

  // ======== Phase B: reduce 2 partials + RoPE (verified R6) ========
  {
    const float* P0 = scratch;
    const float* P1 = scratch + 524288;
    for (int idx = bid * 256 + t; idx < 327680; idx += 65536) {
      if (idx < 196608) {
        int dp = idx & 31;
        int head = (idx >> 5) % 24;
        int s = idx / 768;
        int base = s * 2048 + head * 64;
        int a1 = base + dp, a2 = base + dp + 32;
        float x1 = P0[a1] + P1[a1];
        float x2 = P0[a2] + P1[a2];
        float c1 = cosp[s * 64 + dp],      s1v = sinp[s * 64 + dp];
        float c2 = cosp[s * 64 + dp + 32], s2v = sinp[s * 64 + dp + 32];
        QKV[a1] = x1 * c1 - x2 * s1v;
        QKV[a2] = x2 * c2 + x1 * s2v;
      } else {
        int i2 = idx - 196608;
        int s = i2 >> 9, c = 1536 + (i2 & 511);
        int a = s * 2048 + c;
        QKV[a] = P0[a] + P1[a];
      }
    }
  }
  gg.sync();

  // ======== Phase C: QK^T + softmax (verified R8) ========
  {
    char* kshc = ldsraw;                                   // 32KB bf16 swizzled
    char* qshc = ldsraw + 32768;                           // 2KB
    float (*awsh)[260] = (float(*)[260])(ldsraw + 34816);  // 16.6KB
    const int h = bid >> 4, j = bid & 15;
    const int g = h >> 1;
    #pragma unroll
    for (int i = 0; i < 16; ++i) {
      int row = (t >> 4) + 16 * i;
      int c = (t & 15) * 4;
      float4 kv = *reinterpret_cast<const float4*>(QKV + (size_t)row * 2048 + 1024 + g * 64 + c);
      ushort4 w;
      w.x = f2bf(kv.x); w.y = f2bf(kv.y); w.z = f2bf(kv.z); w.w = f2bf(kv.w);
      *reinterpret_cast<ushort4*>(kshc + row * 128 + ((c * 2) ^ ((row & 7) << 4))) = w;
    }
    {
      int row = t >> 4, c = (t & 15) * 4;
      float4 qv = *reinterpret_cast<const float4*>(QKV + (size_t)(16 * j + row) * 2048 + h * 64 + c);
      ushort4 w;
      w.x = f2bf(qv.x); w.y = f2bf(qv.y); w.z = f2bf(qv.z); w.w = f2bf(qv.w);
      *reinterpret_cast<ushort4*>(qshc + row * 128 + ((c * 2) ^ ((row & 7) << 4))) = w;
    }
    __syncthreads();
    floatx4 acc[4];
    #pragma unroll
    for (int q4 = 0; q4 < 4; ++q4) acc[q4] = (floatx4){0.f, 0.f, 0.f, 0.f};
    #pragma unroll
    for (int q4 = 0; q4 < 4; ++q4) {
      int nt = wid + 4 * q4;
      if (nt <= j) {
        #pragma unroll
        for (int kc = 0; kc < 2; ++kc) {
          short8 af = *reinterpret_cast<const short8*>(
              qshc + lr * 128 + ((kc * 64 + lk * 16) ^ sw));
          int tt = nt * 16 + lr;
          short8 bf = *reinterpret_cast<const short8*>(
              kshc + tt * 128 + ((kc * 64 + lk * 16) ^ ((tt & 7) << 4)));
          acc[q4] = __builtin_amdgcn_mfma_f32_16x16x32_bf16(af, bf, acc[q4], 0, 0, 0);
        }
      }
    }
    #pragma unroll
    for (int q4 = 0; q4 < 4; ++q4) {
      int nt = wid + 4 * q4;
      if (nt <= j) {
        #pragma unroll
        for (int r = 0; r < 4; ++r)
          awsh[lk * 4 + r][nt * 16 + lr] = acc[q4][r];
      }
    }
    __syncthreads();
    for (int rr = 0; rr < 4; ++rr) {
      int row = 4 * wid + rr;
      int s = 16 * j + row;
      float v[4], m = -3.0e38f;
      #pragma unroll
      for (int i = 0; i < 4; ++i) {
        int tc = lane + 64 * i;
        v[i] = (tc <= s) ? awsh[row][tc] * SCALE : -3.0e38f;
        m = fmaxf(m, v[i]);
      }
      #pragma unroll
      for (int off = 32; off; off >>= 1) m = fmaxf(m, __shfl_xor(m, off));
      float e[4], sum = 0.f;
      #pragma unroll
      for (int i = 0; i < 4; ++i) {
        int tc = lane + 64 * i;
        e[i] = (tc <= s) ? __expf(v[i] - m) : 0.f;
        sum += e[i];
      }
      #pragma unroll
      for (int off = 32; off; off >>= 1) sum += __shfl_xor(sum, off);
      float inv = 1.f / sum;
      float p2 = 0.f;
      size_t rowbase = ((size_t)h * 256 + s) * 256;
      #pragma unroll
      for (int i = 0; i < 4; ++i) {
        int tc = lane + 64 * i;
        float pv = e[i] * inv;
        pOut[rowbase + tc] = pv;
        p2 = fmaf(pv, pv, p2);
        if (tc <= s) awf[rowbase + tc] = v[i] * LOG2E;
      }
      #pragma unroll
      for (int off = 32; off; off >>= 1) p2 += __shfl_xor(p2, off);
      if (lane == 0) P2g[h * 256 + s] = p2;
    }
  }
  gg.sync();

  // ======== Phase D: p_diff + PV, fp32 k/v in LDS (numerics fix) ========
  {
    float* kls = (float*)ldsraw;                             // 64KB
    float* vls = (float*)(ldsraw + 65536);                   // 64KB
    float2 (*rb)[2][256] = (float2(*)[2][256])(ldsraw + 131072);  // 16KB
    const int g = bid >> 5, u = bid & 31;
    #pragma unroll
    for (int i = 0; i < 16; ++i) {
      int fi = t + i * 256;
      int tt = fi >> 4, c = (fi & 15) * 4;
      *reinterpret_cast<float4*>(&kls[tt * 64 + c]) =
          *reinterpret_cast<const float4*>(QKV + (size_t)tt * 2048 + 1024 + g * 64 + c);
      *reinterpret_cast<float4*>(&vls[tt * 64 + c]) =
          *reinterpret_cast<const float4*>(QKV + (size_t)tt * 2048 + 1536 + g * 64 + c);
    }
    __syncthreads();
    const int h = 2 * g + (wid & 1);
    for (int ps = 0; ps < 2; ++ps) {
      int jj = 2 * u + (wid >> 1) + 64 * ps;
      for (int r = 0; r < 2; ++r) {
        int s = r ? 255 - jj : jj;
        size_t rowbase = ((size_t)h * 256 + s) * 256;
        #pragma unroll
        for (int i = 0; i < 4; ++i) {
          int idx = lane + i * 64;
          rb[wid][r][idx] = make_float2(awf[rowbase + idx], pOut[rowbase + idx]);
        }
      }
      float qk_acc = 0.f;
      for (int r = 0; r < 2; ++r) {
        int s = r ? 255 - jj : jj;
        float cd2 = (SCALE * LOG2E) * QKV[(size_t)s * 2048 + h * 64 + lane];
        float S1 = 0.f, S2 = 0.f, S3 = 0.f, AV = 0.f;
        const float2* rbr = rb[wid][r];
        for (int tt = 0; tt <= s; ++tt) {
          float kf = kls[tt * 64 + lane];
          float vf = vls[tt * 64 + lane];
          float2 ap = rbr[tt];
          float z2 = fmaf(-cd2, kf, ap.x);
          float e = exp2f(z2);
          S1 += e;
          S2 = fmaf(e, e, S2);
          S3 = fmaf(e, ap.y, S3);
          AV = fmaf(ap.y, vf, AV);
        }
        float inv = 1.f / S1;
        qk_acc += S2 * inv * inv - 2.f * S3 * inv + P2g[h * 256 + s];
        attn_out[(size_t)s * 1024 + h * 64 + lane] = AV;
      }
      qkpart[((size_t)h * 128 + jj) * 64 + lane] = qk_acc;
    }
  }
  gg.sync();

  // ======== Phase E: O GEMM bf16 MFMA, K-split 4 (verified R7) ========
  {
    char* Asc = ldsraw;
    char* Bsc = ldsraw + 8192;
    const int ks = bid >> 6;           // 0..3
    const int tile = bid & 63;         // 4 m x 16 n
    const int tile_n = tile & 15, tile_m = tile >> 4;
    const int n0 = tile_n * 64, m0 = tile_m * 64;
    const int arow = t >> 4, acg = t & 15;
    const int bng = t & 15;
    const int kbeg = ks * 256;
    float4 ra[4], rb0[2], rb1[2];
    auto LOAD = [&](int k0) {
      #pragma unroll
      for (int i = 0; i < 4; ++i)
        ra[i] = *reinterpret_cast<const float4*>(attn_out + (size_t)(m0 + arow + 16 * i) * 1024 + k0 + acg * 4);
      #pragma unroll
      for (int i = 0; i < 2; ++i) {
        int k = 2 * ((t >> 4) + 16 * i);
        rb0[i] = *reinterpret_cast<const float4*>(Wo + (size_t)(k0 + k) * 1024 + n0 + bng * 4);
        rb1[i] = *reinterpret_cast<const float4*>(Wo + (size_t)(k0 + k + 1) * 1024 + n0 + bng * 4);
      }
    };
    LOAD(kbeg);
    const int wr = wid >> 1, wc = wid & 1;
    floatx4 acc[2][2];
    #pragma unroll
    for (int mt = 0; mt < 2; ++mt)
      #pragma unroll
      for (int nt = 0; nt < 2; ++nt)
        acc[mt][nt] = (floatx4){0.f, 0.f, 0.f, 0.f};
    for (int kt = 0; kt < 4; ++kt) {
      #pragma unroll
      for (int i = 0; i < 4; ++i) {
        int row = arow + 16 * i;
        ushort4 w;
        w.x = f2bf(ra[i].x); w.y = f2bf(ra[i].y); w.z = f2bf(ra[i].z); w.w = f2bf(ra[i].w);
        *reinterpret_cast<ushort4*>(Asc + row * 128 + ((acg * 8) ^ ((row & 7) << 4))) = w;
      }
      #pragma unroll
      for (int i = 0; i < 2; ++i) {
        int k = 2 * ((t >> 4) + 16 * i);
        const float* p0 = (const float*)&rb0[i];
        const float* p1 = (const float*)&rb1[i];
        #pragma unroll
        for (int j = 0; j < 4; ++j) {
          int n = bng * 4 + j;
          uint32_t v = (uint32_t)f2bf(p0[j]) | ((uint32_t)f2bf(p1[j]) << 16);
          *reinterpret_cast<uint32_t*>(Bsc + n * 128 + ((k * 2) ^ ((n & 7) << 4))) = v;
        }
      }
      __syncthreads();
      if (kt + 1 < 4) LOAD(kbeg + 64 * (kt + 1));
      #pragma unroll
      for (int kc = 0; kc < 2; ++kc) {
        short8 af[2], bf[2];
        #pragma unroll
        for (int mt = 0; mt < 2; ++mt)
          af[mt] = *reinterpret_cast<const short8*>(
              Asc + (wr * 32 + mt * 16 + lr) * 128 + ((kc * 64 + lk * 16) ^ sw));
        #pragma unroll
        for (int nt = 0; nt < 2; ++nt)
          bf[nt] = *reinterpret_cast<const short8*>(
              Bsc + (wc * 32 + nt * 16 + lr) * 128 + ((kc * 64 + lk * 16) ^ sw));
        #pragma unroll
        for (int mt = 0; mt < 2; ++mt)
          #pragma unroll
          for (int nt = 0; nt < 2; ++nt)
            acc[mt][nt] = __builtin_amdgcn_mfma_f32_16x16x32_bf16(af[mt], bf[nt], acc[mt][nt], 0, 0, 0);
      }
      __syncthreads();
    }
    float* Co = scratch + (size_t)ks * 262144;
    #pragma unroll
    for (int mt = 0; mt < 2; ++mt)
      #pragma unroll
      for (int nt = 0; nt < 2; ++nt)
        #pragma unroll
        for (int r = 0; r < 4; ++r) {
          int row = wr * 32 + mt * 16 + lk * 4 + r;
          int col = wc * 32 + nt * 16 + lr;
          Co[(size_t)(m0 + row) * 1024 + n0 + col] = acc[mt][nt][r];
        }
  }
  gg.sync();

  // ======== Phase F: tail reductions (verified R8 logic) ========
  {
    int tid = bid * 256 + t;
    #pragma unroll
    for (int rep = 0; rep < 4; ++rep) {
      int i = tid + rep * 65536;
      out[i] = scratch[i] + scratch[262144 + i] + scratch[524288 + i] + scratch[786432 + i];
    }
    if (tid < 1024) {
      int h = tid >> 6, d = tid & 63;
      float sum = 0.f;
      for (int j = 0; j < 128; ++j) sum += qkpart[((size_t)h * 128 + j) * 64 + d];
      qki[tid] = sum;
    } else if (tid < 2048) {
      int c = tid - 1024;
      float sum = 0.f;
      for (int s = 0; s < 256; ++s) sum += fabsf(attn_out[(size_t)s * 1024 + c]);
      vi[c] = sum;
      oi[c] = sum;
    }
  }
}

// ---------------------------------------------------------------------------
extern "C" void kernel_launch(void* const* d_in, const int* in_sizes, int n_in,
                              void* d_out, int out_size, void* d_ws, size_t ws_size,
                              hipStream_t stream) {
  const float* X    = (const float*)d_in[0];   // hidden_states (1,256,1024)
  const float* cosp = (const float*)d_in[1];   // (1,256,64)
  const float* sinp = (const float*)d_in[2];   // (1,256,64)
  // d_in[3] attention_mask: causal, implemented analytically
  const float* Wq   = (const float*)d_in[4];   // (1024,1024)
  const float* Wk   = (const float*)d_in[5];   // (1024,512)
  const float* Wv   = (const float*)d_in[6];   // (1024,512)
  const float* Wo   = (const float*)d_in[7];   // (1024,1024)

  float* out  = (float*)d_out;                 // 262144
  float* pOut = out + 262144;                  // 1048576
  float* qki  = pOut + 1048576;                // 1024
  float* vi   = qki + 1024;                    // 1024
  float* oi   = vi + 1024;                     // 1024

  float* ws       = (float*)d_ws;
  float* QKV      = ws;                        // 524288 (s-major, 2048 cols: q|k|v)
  float* P2g      = ws + 524288;               // 4096
  float* attn_out = ws + 528384;               // 262144
  float* qkpart   = ws + 790528;               // 131072
  float* awf      = ws + 921600;               // 1048576 fp32 (aw*scale*log2e)
  float* scratch  = ws + 1970176;              // 1048576 (QKV partials x2; O partials x4)

  void* args[] = {
    (void*)&X, (void*)&cosp, (void*)&sinp, (void*)&Wq, (void*)&Wk, (void*)&Wv,
    (void*)&Wo, (void*)&out, (void*)&pOut, (void*)&qki, (void*)&vi, (void*)&oi,
    (void*)&QKV, (void*)&P2g, (void*)&attn_out, (void*)&qkpart, (void*)&awf,
    (void*)&scratch
  };
  hipLaunchCooperativeKernel((void*)fused_kernel, dim3(256), dim3(256), args, 0, stream);
}

// Round 11
// 59.935 us; speedup vs baseline: 3.6451x; 3.6451x over previous
//
#include <hip/hip_runtime.h>
#include <math.h>

// Problem constants: B=1, S=256, HID=1024, H=16, KV=8, D=64, N_REP=2
#define SCALE 0.125f   // 1/sqrt(64)
#define LOG2E 1.44269504088896340736f

typedef short short8 __attribute__((ext_vector_type(8)));
typedef float floatx4 __attribute__((ext_vector_type(4)));

static __device__ __forceinline__ ushort f2bf(float x) {
  uint32_t b = __float_as_uint(x);
  uint32_t r = (b + 0x7FFFu + ((b >> 16) & 1u)) >> 16;   // RNE
  return (ushort)r;
}
static __device__ __forceinline__ float bf2f(ushort u) {
  return __uint_as_float(((uint32_t)u) << 16);
}

// ---------------------------------------------------------------------------
// MFMA bf16 GEMM 1 + fused RoPE epilogue. Full K=1024 (no split, no partials).
// X(256x1024) @ [Wq|Wk|Wv](1024x2048) -> QKV (RoPE applied to q,k heads).
// 64x64 tile = one head wide, so RoPE pairs (d, d+32) stay in-block: after the
// K-loop the fp32 tile round-trips through LDS to regroup pairs across waves.
// grid = 128 (4 m x 32 n), block = 256.
// ---------------------------------------------------------------------------
__global__ __launch_bounds__(256) void gemm_qkv_rope_kernel(
    const float* __restrict__ X, const float* __restrict__ Wq,
    const float* __restrict__ Wk, const float* __restrict__ Wv,
    const float* __restrict__ cosp, const float* __restrict__ sinp,
    float* __restrict__ QKV) {
  __shared__ __align__(16) char lds[17408];   // As 8K | Bs 8K; reused as Ct[64][68]
  char* Asc = lds;
  char* Bsc = lds + 8192;
  const int bx = blockIdx.x;
  const int tile_n = bx & 31, tile_m = bx >> 5;
  const int n0 = tile_n * 64, m0 = tile_m * 64;
  const float* Bp; int ldb, bc0;
  if (n0 < 1024)      { Bp = Wq; ldb = 1024; bc0 = n0; }
  else if (n0 < 1536) { Bp = Wk; ldb = 512;  bc0 = n0 - 1024; }
  else                { Bp = Wv; ldb = 512;  bc0 = n0 - 1536; }
  const int t = threadIdx.x;
  const int arow = t >> 4, acg = t & 15;
  const int bng = t & 15;
  float4 ra[4], rb0[2], rb1[2];
  auto LOAD = [&](int k0) {
    #pragma unroll
    for (int i = 0; i < 4; ++i)
      ra[i] = *reinterpret_cast<const float4*>(X + (size_t)(m0 + arow + 16 * i) * 1024 + k0 + acg * 4);
    #pragma unroll
    for (int i = 0; i < 2; ++i) {
      int k = 2 * ((t >> 4) + 16 * i);
      rb0[i] = *reinterpret_cast<const float4*>(Bp + (size_t)(k0 + k) * ldb + bc0 + bng * 4);
      rb1[i] = *reinterpret_cast<const float4*>(Bp + (size_t)(k0 + k + 1) * ldb + bc0 + bng * 4);
    }
  };
  LOAD(0);
  const int wid = t >> 6, wr = wid >> 1, wc = wid & 1, lane = t & 63;
  const int lr = lane & 15, lk = lane >> 4;
  const int sw = (lr & 7) << 4;
  floatx4 acc[2][2];
  #pragma unroll
  for (int mt = 0; mt < 2; ++mt)
    #pragma unroll
    for (int nt = 0; nt < 2; ++nt)
      acc[mt][nt] = (floatx4){0.f, 0.f, 0.f, 0.f};
  for (int kt = 0; kt < 16; ++kt) {
    #pragma unroll
    for (int i = 0; i < 4; ++i) {
      int row = arow + 16 * i;
      ushort4 w;
      w.x = f2bf(ra[i].x); w.y = f2bf(ra[i].y); w.z = f2bf(ra[i].z); w.w = f2bf(ra[i].w);
      *reinterpret_cast<ushort4*>(Asc + row * 128 + ((acg * 8) ^ ((row & 7) << 4))) = w;
    }
    #pragma unroll
    for (int i = 0; i < 2; ++i) {
      int k = 2 * ((t >> 4) + 16 * i);
      const float* p0 = (const float*)&rb0[i];
      const float* p1 = (const float*)&rb1[i];
      #pragma unroll
      for (int j = 0; j < 4; ++j) {
        int n = bng * 4 + j;
        uint32_t v = (uint32_t)f2bf(p0[j]) | ((uint32_t)f2bf(p1[j]) << 16);
        *reinterpret_cast<uint32_t*>(Bsc + n * 128 + ((k * 2) ^ ((n & 7) << 4))) = v;
      }
    }
    __syncthreads();
    if (kt + 1 < 16) LOAD(64 * (kt + 1));
    #pragma unroll
    for (int kc = 0; kc < 2; ++kc) {
      short8 af[2], bf[2];
      #pragma unroll
      for (int mt = 0; mt < 2; ++mt)
        af[mt] = *reinterpret_cast<const short8*>(
            Asc + (wr * 32 + mt * 16 + lr) * 128 + ((kc * 64 + lk * 16) ^ sw));
      #pragma unroll
      for (int nt = 0; nt < 2; ++nt)
        bf[nt] = *reinterpret_cast<const short8*>(
            Bsc + (wc * 32 + nt * 16 + lr) * 128 + ((kc * 64 + lk * 16) ^ sw));
      #pragma unroll
      for (int mt = 0; mt < 2; ++mt)
        #pragma unroll
        for (int nt = 0; nt < 2; ++nt)
          acc[mt][nt] = __builtin_amdgcn_mfma_f32_16x16x32_bf16(af[mt], bf[nt], acc[mt][nt], 0, 0, 0);
    }
    __syncthreads();
  }
  if (n0 < 1536) {
    // RoPE epilogue: regroup pairs (d, d+32) via LDS round-trip.
    float (*Ct)[68] = (float(*)[68])lds;
    #pragma unroll
    for (int mt = 0; mt < 2; ++mt)
      #pragma unroll
      for (int nt = 0; nt < 2; ++nt)
        #pragma unroll
        for (int r = 0; r < 4; ++r)
          Ct[wr * 32 + mt * 16 + lk * 4 + r][wc * 32 + nt * 16 + lr] = acc[mt][nt][r];
    __syncthreads();
    #pragma unroll
    for (int i = 0; i < 8; ++i) {
      int pid = t + i * 256;            // 2048 pairs: 64 rows x 32 dp
      int row = pid >> 5, dp = pid & 31;
      float x1 = Ct[row][dp], x2 = Ct[row][dp + 32];
      int s = m0 + row;
      float c1 = cosp[s * 64 + dp],      s1v = sinp[s * 64 + dp];
      float c2 = cosp[s * 64 + dp + 32], s2v = sinp[s * 64 + dp + 32];
      QKV[(size_t)s * 2048 + n0 + dp]      = x1 * c1 - x2 * s1v;
      QKV[(size_t)s * 2048 + n0 + dp + 32] = x2 * c2 + x1 * s2v;
    }
  } else {
    // v tile: direct store
    #pragma unroll
    for (int mt = 0; mt < 2; ++mt)
      #pragma unroll
      for (int nt = 0; nt < 2; ++nt)
        #pragma unroll
        for (int r = 0; r < 4; ++r) {
          int row = wr * 32 + mt * 16 + lk * 4 + r;
          int col = wc * 32 + nt * 16 + lr;
          QKV[(size_t)(m0 + row) * 2048 + n0 + col] = acc[mt][nt][r];
        }
  }
}

// ---------------------------------------------------------------------------
// Fused QK^T + softmax (verified R8). One WG per (h, 16-row strip j).
// Writes p (fp32), P2 = sum p^2, awf = fp32(aw*scale*log2e).
// grid = 256 (h*16 + j), block = 256.
// ---------------------------------------------------------------------------
__global__ __launch_bounds__(256) void qk_sm_kernel(
    const float* __restrict__ QKV, float* __restrict__ pOut,
    float* __restrict__ awf, float* __restrict__ P2) {
  __shared__ ushort ksh[16384];      // 32KB swizzled [t][d]
  __shared__ ushort qsh[1024];       // 2KB  swizzled [r][d]
  __shared__ float awsh[16][260];    // padded: conflict-free col reads
  char* kshc = (char*)ksh;
  char* qshc = (char*)qsh;
  const int h = blockIdx.x >> 4, j = blockIdx.x & 15;
  const int g = h >> 1;
  const int t = threadIdx.x;
  #pragma unroll
  for (int i = 0; i < 16; ++i) {     // stage ALL k rows (bf16, XOR swizzle)
    int row = (t >> 4) + 16 * i;
    int c = (t & 15) * 4;
    float4 kv = *reinterpret_cast<const float4*>(QKV + (size_t)row * 2048 + 1024 + g * 64 + c);
    ushort4 w;
    w.x = f2bf(kv.x); w.y = f2bf(kv.y); w.z = f2bf(kv.z); w.w = f2bf(kv.w);
    *reinterpret_cast<ushort4*>(kshc + row * 128 + ((c * 2) ^ ((row & 7) << 4))) = w;
  }
  { // stage q strip (16 rows)
    int row = t >> 4, c = (t & 15) * 4;
    float4 qv = *reinterpret_cast<const float4*>(QKV + (size_t)(16 * j + row) * 2048 + h * 64 + c);
    ushort4 w;
    w.x = f2bf(qv.x); w.y = f2bf(qv.y); w.z = f2bf(qv.z); w.w = f2bf(qv.w);
    *reinterpret_cast<ushort4*>(qshc + row * 128 + ((c * 2) ^ ((row & 7) << 4))) = w;
  }
  __syncthreads();
  const int w = t >> 6, lane = t & 63;
  const int lr = lane & 15, lk = lane >> 4;
  const int sw = (lr & 7) << 4;
  floatx4 acc[4];
  #pragma unroll
  for (int q4 = 0; q4 < 4; ++q4) acc[q4] = (floatx4){0.f, 0.f, 0.f, 0.f};
  #pragma unroll
  for (int q4 = 0; q4 < 4; ++q4) {
    int nt = w + 4 * q4;
    if (nt <= j) {
      #pragma unroll
      for (int kc = 0; kc < 2; ++kc) {
        short8 af = *reinterpret_cast<const short8*>(
            qshc + lr * 128 + ((kc * 64 + lk * 16) ^ sw));
        int tt = nt * 16 + lr;
        short8 bf = *reinterpret_cast<const short8*>(
            kshc + tt * 128 + ((kc * 64 + lk * 16) ^ ((tt & 7) << 4)));
        acc[q4] = __builtin_amdgcn_mfma_f32_16x16x32_bf16(af, bf, acc[q4], 0, 0, 0);
      }
    }
  }
  #pragma unroll
  for (int q4 = 0; q4 < 4; ++q4) {
    int nt = w + 4 * q4;
    if (nt <= j) {
      #pragma unroll
      for (int r = 0; r < 4; ++r)
        awsh[lk * 4 + r][nt * 16 + lr] = acc[q4][r];
    }
  }
  __syncthreads();
  for (int rr = 0; rr < 4; ++rr) {
    int row = 4 * w + rr;
    int s = 16 * j + row;
    float v[4], m = -3.0e38f;
    #pragma unroll
    for (int i = 0; i < 4; ++i) {
      int tc = lane + 64 * i;
      v[i] = (tc <= s) ? awsh[row][tc] * SCALE : -3.0e38f;
      m = fmaxf(m, v[i]);
    }
    #pragma unroll
    for (int off = 32; off; off >>= 1) m = fmaxf(m, __shfl_xor(m, off));
    float e[4], sum = 0.f;
    #pragma unroll
    for (int i = 0; i < 4; ++i) {
      int tc = lane + 64 * i;
      e[i] = (tc <= s) ? __expf(v[i] - m) : 0.f;
      sum += e[i];
    }
    #pragma unroll
    for (int off = 32; off; off >>= 1) sum += __shfl_xor(sum, off);
    float inv = 1.f / sum;
    float p2 = 0.f;
    size_t rowbase = ((size_t)h * 256 + s) * 256;
    #pragma unroll
    for (int i = 0; i < 4; ++i) {
      int tc = lane + 64 * i;
      float pv = e[i] * inv;
      pOut[rowbase + tc] = pv;
      p2 = fmaf(pv, pv, p2);
      if (tc <= s) awf[rowbase + tc] = v[i] * LOG2E;
    }
    #pragma unroll
    for (int off = 32; off; off >>= 1) p2 += __shfl_xor(p2, off);
    if (lane == 0) P2[h * 256 + s] = p2;
  }
}

// ---------------------------------------------------------------------------
// Merged p_diff + PV, FP32 k AND v in LDS (numerics fix: bf16 V was the
// 0.844 absmax source — correlated rounding summed over 256 |attn_out|).
// 512 threads (8 waves -> 2 waves/SIMD at 1 WG/CU with 152KB LDS).
// wave w: h = 2g+(w&1), jj = 4u+(w>>1); rows jj and 255-jj.
// grid = 256 (8 g * 32 u), block = 512.
// ---------------------------------------------------------------------------
__global__ __launch_bounds__(512) void pdiff_attnv_kernel(
    const float* __restrict__ QKV, const float* __restrict__ awf,
    const float* __restrict__ p, const float* __restrict__ P2,
    float* __restrict__ qkpart, float* __restrict__ attn_out) {
  __shared__ float kls[16384];         // 64KB fp32 [t][d]
  __shared__ float vls[16384];         // 64KB fp32 [t][d]
  __shared__ float rbp[8][2][256];     // 16KB p_t per wave-row
  __shared__ ushort rbw[8][2][256];    // 8KB  bf16(awf_t) per wave-row
  int g = blockIdx.x >> 5;
  int u = blockIdx.x & 31;
  int t = threadIdx.x;
  #pragma unroll
  for (int i = 0; i < 8; ++i) {
    int fi = t + i * 512;              // 4096 float4 slots
    int tt = fi >> 4, c = (fi & 15) * 4;
    *reinterpret_cast<float4*>(&kls[tt * 64 + c]) =
        *reinterpret_cast<const float4*>(QKV + (size_t)tt * 2048 + 1024 + g * 64 + c);
    *reinterpret_cast<float4*>(&vls[tt * 64 + c]) =
        *reinterpret_cast<const float4*>(QKV + (size_t)tt * 2048 + 1536 + g * 64 + c);
  }
  int w = t >> 6, lane = t & 63;
  int h = 2 * g + (w & 1);
  int jj = 4 * u + (w >> 1);
  for (int r = 0; r < 2; ++r) {
    int s = r ? 255 - jj : jj;
    size_t rowbase = ((size_t)h * 256 + s) * 256;
    #pragma unroll
    for (int i = 0; i < 4; ++i) {
      int idx = lane + i * 64;
      rbw[w][r][idx] = f2bf(awf[rowbase + idx]);
      rbp[w][r][idx] = p[rowbase + idx];
    }
  }
  __syncthreads();
  float qk_acc = 0.f;
  for (int r = 0; r < 2; ++r) {
    int s = r ? 255 - jj : jj;
    float cd2 = (SCALE * LOG2E) * QKV[(size_t)s * 2048 + h * 64 + lane];
    float S1 = 0.f, S2 = 0.f, S3 = 0.f, AV = 0.f;
    const float* pr = rbp[w][r];
    const ushort* ar = rbw[w][r];
    for (int tt = 0; tt <= s; ++tt) {
      float kf = kls[tt * 64 + lane];
      float vf = vls[tt * 64 + lane];
      float pv = pr[tt];
      float z2 = fmaf(-cd2, kf, bf2f(ar[tt]));
      float e = exp2f(z2);
      S1 += e;
      S2 = fmaf(e, e, S2);
      S3 = fmaf(e, pv, S3);
      AV = fmaf(pv, vf, AV);
    }
    float inv = 1.f / S1;
    qk_acc += S2 * inv * inv - 2.f * S3 * inv + P2[h * 256 + s];
    attn_out[(size_t)s * 1024 + h * 64 + lane] = AV;
  }
  qkpart[((size_t)h * 128 + jj) * 64 + lane] = qk_acc;
}

// ---------------------------------------------------------------------------
// MFMA bf16 GEMM 2: attn_out(256x1024) @ Wo(1024x1024) -> out partials.
// K-split 8. grid = 512 (8 ks * 64 tiles), block = 256.  (verified R8)
// ---------------------------------------------------------------------------
__global__ __launch_bounds__(256) void gemm_o_kernel(
    const float* __restrict__ A, const float* __restrict__ W,
    float* __restrict__ Cp) {
  __shared__ ushort As[4096];
  __shared__ ushort Bs[4096];
  char* Asc = (char*)As;
  char* Bsc = (char*)Bs;
  const int bx = blockIdx.x;
  const int ks = bx >> 6;            // 0..7
  const int tile = bx & 63;          // 4 m x 16 n
  const int tile_n = tile & 15, tile_m = tile >> 4;
  const int n0 = tile_n * 64, m0 = tile_m * 64;
  const int t = threadIdx.x;
  const int arow = t >> 4, acg = t & 15;
  const int bng = t & 15;
  const int kbeg = ks * 128;
  float4 ra[4], rb0[2], rb1[2];
  auto LOAD = [&](int k0) {
    #pragma unroll
    for (int i = 0; i < 4; ++i)
      ra[i] = *reinterpret_cast<const float4*>(A + (size_t)(m0 + arow + 16 * i) * 1024 + k0 + acg * 4);
    #pragma unroll
    for (int i = 0; i < 2; ++i) {
      int k = 2 * ((t >> 4) + 16 * i);
      rb0[i] = *reinterpret_cast<const float4*>(W + (size_t)(k0 + k) * 1024 + n0 + bng * 4);
      rb1[i] = *reinterpret_cast<const float4*>(W + (size_t)(k0 + k + 1) * 1024 + n0 + bng * 4);
    }
  };
  LOAD(kbeg);
  const int wid = t >> 6, wr = wid >> 1, wc = wid & 1, lane = t & 63;
  const int lr = lane & 15, lk = lane >> 4;
  const int sw = (lr & 7) << 4;
  floatx4 acc[2][2];
  #pragma unroll
  for (int mt = 0; mt < 2; ++mt)
    #pragma unroll
    for (int nt = 0; nt < 2; ++nt)
      acc[mt][nt] = (floatx4){0.f, 0.f, 0.f, 0.f};
  for (int kt = 0; kt < 2; ++kt) {
    #pragma unroll
    for (int i = 0; i < 4; ++i) {
      int row = arow + 16 * i;
      ushort4 w;
      w.x = f2bf(ra[i].x); w.y = f2bf(ra[i].y); w.z = f2bf(ra[i].z); w.w = f2bf(ra[i].w);
      *reinterpret_cast<ushort4*>(Asc + row * 128 + ((acg * 8) ^ ((row & 7) << 4))) = w;
    }
    #pragma unroll
    for (int i = 0; i < 2; ++i) {
      int k = 2 * ((t >> 4) + 16 * i);
      const float* p0 = (const float*)&rb0[i];
      const float* p1 = (const float*)&rb1[i];
      #pragma unroll
      for (int j = 0; j < 4; ++j) {
        int n = bng * 4 + j;
        uint32_t v = (uint32_t)f2bf(p0[j]) | ((uint32_t)f2bf(p1[j]) << 16);
        *reinterpret_cast<uint32_t*>(Bsc + n * 128 + ((k * 2) ^ ((n & 7) << 4))) = v;
      }
    }
    __syncthreads();
    if (kt + 1 < 2) LOAD(kbeg + 64 * (kt + 1));
    #pragma unroll
    for (int kc = 0; kc < 2; ++kc) {
      short8 af[2], bf[2];
      #pragma unroll
      for (int mt = 0; mt < 2; ++mt)
        af[mt] = *reinterpret_cast<const short8*>(
            Asc + (wr * 32 + mt * 16 + lr) * 128 + ((kc * 64 + lk * 16) ^ sw));
      #pragma unroll
      for (int nt = 0; nt < 2; ++nt)
        bf[nt] = *reinterpret_cast<const short8*>(
            Bsc + (wc * 32 + nt * 16 + lr) * 128 + ((kc * 64 + lk * 16) ^ sw));
      #pragma unroll
      for (int mt = 0; mt < 2; ++mt)
        #pragma unroll
        for (int nt = 0; nt < 2; ++nt)
          acc[mt][nt] = __builtin_amdgcn_mfma_f32_16x16x32_bf16(af[mt], bf[nt], acc[mt][nt], 0, 0, 0);
    }
    __syncthreads();
  }
  float* Co = Cp + (size_t)ks * 262144;
  #pragma unroll
  for (int mt = 0; mt < 2; ++mt)
    #pragma unroll
    for (int nt = 0; nt < 2; ++nt)
      #pragma unroll
      for (int r = 0; r < 4; ++r) {
        int row = wr * 32 + mt * 16 + lk * 4 + r;
        int col = wc * 32 + nt * 16 + lr;
        Co[(size_t)(m0 + row) * 1024 + n0 + col] = acc[mt][nt][r];
      }
}

// ---------------------------------------------------------------------------
// Tail: blocks 0..1023 o_reduce (8 partials); 1024..1027 qk_importance;
// 1028..1031 v/o importance. grid = 1032, block = 256.  (verified R8)
// ---------------------------------------------------------------------------
__global__ __launch_bounds__(256) void tail_all_kernel(
    const float* __restrict__ Op, const float* __restrict__ qkpart,
    const float* __restrict__ attn_out, float* __restrict__ out,
    float* __restrict__ qkout, float* __restrict__ vout, float* __restrict__ oout) {
  int b = blockIdx.x, t = threadIdx.x;
  if (b < 1024) {
    int i = b * 256 + t;               // 262144
    float s = 0.f;
    #pragma unroll
    for (int k = 0; k < 8; ++k) s += Op[(size_t)k * 262144 + i];
    out[i] = s;
  } else if (b < 1028) {
    int idx = (b - 1024) * 256 + t;    // 1024 = h*64+d
    int h = idx >> 6, d = idx & 63;
    float sum = 0.f;
    for (int j = 0; j < 128; ++j) sum += qkpart[((size_t)h * 128 + j) * 64 + d];
    qkout[idx] = sum;
  } else {
    int c = (b - 1028) * 256 + t;      // 1024
    float sum = 0.f;
    for (int s = 0; s < 256; ++s) sum += fabsf(attn_out[(size_t)s * 1024 + c]);
    vout[c] = sum;
    oout[c] = sum;
  }
}

// ---------------------------------------------------------------------------
extern "C" void kernel_launch(void* const* d_in, const int* in_sizes, int n_in,
                              void* d_out, int out_size, void* d_ws, size_t ws_size,
                              hipStream_t stream) {
  const float* X    = (const float*)d_in[0];   // hidden_states (1,256,1024)
  const float* cosp = (const float*)d_in[1];   // (1,256,64)
  const float* sinp = (const float*)d_in[2];   // (1,256,64)
  // d_in[3] attention_mask: causal, implemented analytically
  const float* Wq   = (const float*)d_in[4];   // (1024,1024)
  const float* Wk   = (const float*)d_in[5];   // (1024,512)
  const float* Wv   = (const float*)d_in[6];   // (1024,512)
  const float* Wo   = (const float*)d_in[7];   // (1024,1024)

  float* out  = (float*)d_out;                 // 262144
  float* pOut = out + 262144;                  // 1048576
  float* qki  = pOut + 1048576;                // 1024
  float* vi   = qki + 1024;                    // 1024
  float* oi   = vi + 1024;                     // 1024

  float* ws       = (float*)d_ws;
  float* QKV      = ws;                        // 524288 (s-major, 2048 cols: q|k|v)
  float* P2       = ws + 524288;               // 4096
  float* attn_out = ws + 528384;               // 262144
  float* qkpart   = ws + 790528;               // 131072
  float* awf      = ws + 921600;               // 1048576 fp32 (aw*scale*log2e)
  float* scratch  = ws + 1970176;              // 2097152 (O partials x8)

  hipLaunchKernelGGL(gemm_qkv_rope_kernel, dim3(128), dim3(256), 0, stream, X, Wq, Wk, Wv, cosp, sinp, QKV);
  hipLaunchKernelGGL(qk_sm_kernel, dim3(256), dim3(256), 0, stream, QKV, pOut, awf, P2);
  hipLaunchKernelGGL(pdiff_attnv_kernel, dim3(256), dim3(512), 0, stream, QKV, awf, pOut, P2, qkpart, attn_out);
  hipLaunchKernelGGL(gemm_o_kernel, dim3(512), dim3(256), 0, stream, attn_out, Wo, scratch);
  hipLaunchKernelGGL(tail_all_kernel, dim3(1032), dim3(256), 0, stream, scratch, qkpart, attn_out, out, qki, vi, oi);
}